// Round 1
// baseline (64.175 us; speedup 1.0000x reference)
//
#include <hip/hip_runtime.h>
#include <math.h>

#define DD 256
#define DEPTH 4
#define RDIM 16
#define NDIM 16
#define XDBL 48

// Entire network evaluated for the cls position only (position 0):
//  - causal conv at l=0 reduces to conv_w[d,3]*x_in[d]
//  - scan at t=0: state=0 -> y0[d] = dt[d]*x_c[d]*sum_n(B[n]*C[n]); A_log unused
//  - input vector = cls_token + pos_embed[:, -1, :], identical for all batches
// Output = broadcast of the final rmsnorm'd vector to all 256 rows.
__launch_bounds__(1024, 1)
__global__ void netmamba_cls_kernel(
    const float* __restrict__ cls_token,
    const float* __restrict__ pos_embed,
    const float* __restrict__ norm_w,
    const float* __restrict__ in_proj_w,
    const float* __restrict__ conv_w,
    const float* __restrict__ conv_b,
    const float* __restrict__ x_proj_w,
    const float* __restrict__ dt_proj_w,
    const float* __restrict__ dt_proj_b,
    const float* __restrict__ D_skip,
    const float* __restrict__ out_proj_w,
    const float* __restrict__ norm_f_w,
    float* __restrict__ out)
{
    const int tid = threadIdx.x;
    __shared__ float res[DD], hv[DD], hn[DD], xc[DD], zv[DD], yv[DD];
    __shared__ float xdbl[XDBL];
    __shared__ float4 part[8][128];     // 16 KB, reused by out_proj as [16][64]
    __shared__ float xpart[XDBL][16];   // 3 KB
    __shared__ float red[4];
    __shared__ float rstd_s;

    if (tid < DD) {
        hv[tid]  = cls_token[tid] + pos_embed[50 * DD + tid];
        res[tid] = 0.f;
    }
    __syncthreads();

    for (int L = 0; L < DEPTH; ++L) {
        // ---- residual += h ----
        if (tid < DD) res[tid] += hv[tid];
        __syncthreads();

        // ---- rmsnorm(res, norm_w[L]) -> hn ----
        {
            float x = (tid < DD) ? res[tid] : 0.f;
            float ss = x * x;
            #pragma unroll
            for (int o = 32; o > 0; o >>= 1) ss += __shfl_down(ss, o, 64);
            if (tid < DD && (tid & 63) == 0) red[tid >> 6] = ss;
            __syncthreads();
            if (tid == 0)
                rstd_s = rsqrtf((red[0] + red[1] + red[2] + red[3]) * (1.f / DD) + 1e-5f);
            __syncthreads();
            if (tid < DD) hn[tid] = res[tid] * rstd_s * norm_w[L * DD + tid];
        }
        __syncthreads();

        // ---- in_proj: xz[512] = hn @ W(256x512); fused conv@t0 + silu ----
        {
            const float4* W4 = (const float4*)(in_proj_w + (size_t)L * DD * 2 * DD);
            int p  = tid >> 7;    // 0..7  : d-range [p*32, p*32+32)
            int jg = tid & 127;   // float4 column group (512 cols / 4)
            float4 acc = make_float4(0.f, 0.f, 0.f, 0.f);
            #pragma unroll 8
            for (int i = 0; i < 32; ++i) {
                int d = p * 32 + i;
                float h = hn[d];                 // wave-uniform broadcast
                float4 w = W4[d * 128 + jg];     // coalesced 1KB/wave
                acc.x += h * w.x; acc.y += h * w.y;
                acc.z += h * w.z; acc.w += h * w.w;
            }
            part[p][jg] = acc;
        }
        __syncthreads();
        if (tid < 2 * DD) {
            int j = tid;
            float s = 0.f;
            #pragma unroll
            for (int p = 0; p < 8; ++p) {
                const float* pp = (const float*)&part[p][j >> 2];
                s += pp[j & 3];
            }
            if (j < DD) {
                float pre = conv_w[(L * DD + j) * 4 + 3] * s + conv_b[L * DD + j];
                xc[j] = pre / (1.f + __expf(-pre));      // silu
            } else {
                zv[j - DD] = s;
            }
        }
        __syncthreads();

        // ---- x_proj: xdbl[48] = xc @ Wx(256x48) ----
        if (tid < 768) {
            int j   = tid >> 4;   // 0..47
            int seg = tid & 15;   // 16 partials of 16 MACs
            const float* Wx = x_proj_w + (size_t)L * DD * XDBL;
            float acc = 0.f;
            #pragma unroll
            for (int q = 0; q < 16; ++q) {
                int d = seg * 16 + q;
                acc += xc[d] * Wx[d * XDBL + j];
            }
            xpart[j][seg] = acc;
        }
        __syncthreads();
        if (tid < XDBL) {
            float s = 0.f;
            #pragma unroll
            for (int k = 0; k < 16; ++k) s += xpart[tid][k];
            xdbl[tid] = s;
        }
        __syncthreads();

        // ---- dt_proj + softplus + scan(t=0) + skip + gate -> yv ----
        if (tid < DD) {
            const float* Wdt = dt_proj_w + (size_t)L * RDIM * DD;
            float acc = dt_proj_b[L * DD + tid];
            #pragma unroll
            for (int r = 0; r < RDIM; ++r) acc += xdbl[r] * Wdt[r * DD + tid];
            float dt = fmaxf(acc, 0.f) + log1pf(__expf(-fabsf(acc)));  // softplus
            float s = 0.f;
            #pragma unroll
            for (int n = 0; n < NDIM; ++n)
                s += xdbl[RDIM + n] * xdbl[RDIM + NDIM + n];           // B·C
            float y = (dt * s + D_skip[L * DD + tid]) * xc[tid];
            float z = zv[tid];
            yv[tid] = y * (z / (1.f + __expf(-z)));                    // * silu(z)
        }
        __syncthreads();

        // ---- out_proj: hv[256] = yv @ Wo(256x256) ----
        {
            const float4* Wo = (const float4*)(out_proj_w + (size_t)L * DD * DD);
            int p  = tid >> 6;    // 0..15 : d-range [p*16, p*16+16)
            int jg = tid & 63;    // float4 column group (256 cols / 4)
            float4 acc = make_float4(0.f, 0.f, 0.f, 0.f);
            #pragma unroll 8
            for (int i = 0; i < 16; ++i) {
                int d = p * 16 + i;
                float y = yv[d];
                float4 w = Wo[d * 64 + jg];
                acc.x += y * w.x; acc.y += y * w.y;
                acc.z += y * w.z; acc.w += y * w.w;
            }
            ((float4*)part)[p * 64 + jg] = acc;
        }
        __syncthreads();
        if (tid < DD) {
            int j = tid;
            float s = 0.f;
            const float4* pb = (const float4*)part;
            #pragma unroll
            for (int p = 0; p < 16; ++p) {
                const float* pp = (const float*)&pb[p * 64 + (j >> 2)];
                s += pp[j & 3];
            }
            hv[j] = s;
        }
        __syncthreads();
    }

    // ---- final rmsnorm(hv, norm_f_w) -> hn ----
    {
        float x = (tid < DD) ? hv[tid] : 0.f;
        float ss = x * x;
        #pragma unroll
        for (int o = 32; o > 0; o >>= 1) ss += __shfl_down(ss, o, 64);
        if (tid < DD && (tid & 63) == 0) red[tid >> 6] = ss;
        __syncthreads();
        if (tid == 0)
            rstd_s = rsqrtf((red[0] + red[1] + red[2] + red[3]) * (1.f / DD) + 1e-5f);
        __syncthreads();
        if (tid < DD) hn[tid] = hv[tid] * rstd_s * norm_f_w[tid];
    }
    __syncthreads();

    // ---- broadcast write: 256 identical rows ----
    {
        const float4* o4 = (const float4*)hn;
        float4* out4 = (float4*)out;
        for (int idx = tid; idx < 256 * 64; idx += 1024)
            out4[idx] = o4[idx & 63];
    }
}

extern "C" void kernel_launch(void* const* d_in, const int* in_sizes, int n_in,
                              void* d_out, int out_size, void* d_ws, size_t ws_size,
                              hipStream_t stream) {
    // setup_inputs order:
    // 0 x, 1 proj_w, 2 proj_b, 3 cls_token, 4 pos_embed, 5 norm_w, 6 in_proj_w,
    // 7 conv_w, 8 conv_b, 9 x_proj_w, 10 dt_proj_w, 11 dt_proj_b, 12 A_log,
    // 13 D_skip, 14 out_proj_w, 15 norm_f_w
    netmamba_cls_kernel<<<dim3(1), dim3(1024), 0, stream>>>(
        (const float*)d_in[3],   // cls_token
        (const float*)d_in[4],   // pos_embed
        (const float*)d_in[5],   // norm_w
        (const float*)d_in[6],   // in_proj_w
        (const float*)d_in[7],   // conv_w
        (const float*)d_in[8],   // conv_b
        (const float*)d_in[9],   // x_proj_w
        (const float*)d_in[10],  // dt_proj_w
        (const float*)d_in[11],  // dt_proj_b
        (const float*)d_in[13],  // D_skip
        (const float*)d_in[14],  // out_proj_w
        (const float*)d_in[15],  // norm_f_w
        (float*)d_out);
}